// Round 10
// baseline (320.909 us; speedup 1.0000x reference)
//
#include <hip/hip_runtime.h>

#define NN 32768      // total nodes
#define NP 512        // nodes per graph
#define NB 64         // graphs
#define NE 1048576    // edges
#define FIN 16
#define H 128
#define BN_EPS 1e-5f
#define EPB 4096      // edges per hist/scatterA block
#define NBLK (NE / EPB)   // 256
#define CAPH 8704     // max edges per half-graph
#define NSH 16        // BN shadow copies

typedef unsigned int u32;
typedef unsigned short u16;
typedef __attribute__((ext_vector_type(8))) short bf16x8;
typedef __attribute__((ext_vector_type(4))) float f32x4;

__device__ __forceinline__ u16 f2bf(float f) {
    u32 u = __float_as_uint(f);
    return (u16)((u + 0x7fffu + ((u >> 16) & 1u)) >> 16);
}
__device__ __forceinline__ float bfLo(u32 p) { return __uint_as_float(p << 16); }
__device__ __forceinline__ float bfHi(u32 p) { return __uint_as_float(p & 0xffff0000u); }
__device__ __forceinline__ float b2f(u16 v) { return __uint_as_float((u32)v << 16); }

// ---------------- workspace layout (bytes) ----------------
static constexpr size_t SZ_HALF   = (size_t)NN * H * 2;            // 8 MiB
static constexpr size_t OFF_X     = 0;
static constexpr size_t OFF_TMP   = OFF_X + SZ_HALF;               // int2 tmp (8 MiB)
static constexpr size_t OFF_Y     = OFF_TMP;                       // bufY aliases tmp (dead after sortB)
static constexpr size_t OFF_SORT  = OFF_TMP + (size_t)NE * 8;      // NE int2 (8 MiB)
static constexpr size_t OFF_OFFS  = OFF_SORT + (size_t)NE * 8;     // NN+8 ints
static constexpr size_t OFF_HISTG = OFF_OFFS + ((size_t)NN + 128) * 4;
static constexpr size_t OFF_STARTG= OFF_HISTG + (size_t)NBLK * NB * 4;
static constexpr size_t OFF_GBASE = OFF_STARTG + (size_t)NBLK * NB * 4;  // 65 ints
static constexpr size_t OFF_WT1   = OFF_GBASE + 512;               // 64 KiB
static constexpr size_t OFF_WT2   = OFF_WT1 + (size_t)H * 2 * H * 2;
static constexpr size_t OFF_S     = OFF_WT2 + (size_t)H * 2 * H * 2;   // NN*2 f32
// --- zeroed region (one memset) ---
static constexpr size_t OFF_ZERO  = OFF_S + (size_t)NN * 2 * 4;
static constexpr size_t OFF_NUM   = OFF_ZERO;                      // NB f32
static constexpr size_t OFF_DEN   = OFF_NUM + 256;
static constexpr size_t OFF_GST   = OFF_DEN + 256;                 // 3*NB f32 (atomic)
static constexpr size_t OFF_CTR   = OFF_GST + 1024;                // 1 int
static constexpr size_t OFF_BN    = OFF_CTR + 256;                 // 2 layers * NSH * 2 * H f32
static constexpr size_t SZ_BNL    = (size_t)NSH * 2 * H * 4;
static constexpr size_t OFF_POOL  = OFF_BN + 2 * SZ_BNL;           // NB*2*H f32
static constexpr size_t ZERO_BYTES= (OFF_POOL + (size_t)NB * 2 * H * 4) - OFF_ZERO;

// ---------------- kernels ----------------

// fused prologue: [0,2048) x0 = nf@W_pre+b_pre ; [2048,2304) WT prep ; [2304,2560) hist
__global__ __launch_bounds__(256) void k_prep(
        const float* __restrict__ nf, const float* __restrict__ Wp,
        const float* __restrict__ bp,
        const float* __restrict__ W1_rel, const float* __restrict__ W1_root,
        const float* __restrict__ W2_rel, const float* __restrict__ W2_root,
        const int* __restrict__ src,
        u16* __restrict__ x0, u16* __restrict__ WT1, u16* __restrict__ WT2,
        int* __restrict__ histG) {
    int t = threadIdx.x, bid = blockIdx.x;
    if (bid < 2048) {                       // ---- pre: 16 nodes per block
        __shared__ float sW[FIN * H];
        __shared__ float sNF[16 * FIN];
        for (int i = t; i < FIN * H; i += 256) sW[i] = Wp[i];
        int n0 = bid * 16;
        sNF[t] = nf[n0 * FIN + t];
        __syncthreads();
        int col = t & 127, half = t >> 7;
        float b = bp[col];
        #pragma unroll
        for (int r = 0; r < 8; ++r) {
            int rr = half * 8 + r;
            float acc = b;
            #pragma unroll
            for (int f = 0; f < FIN; ++f) acc += sNF[rr * FIN + f] * sW[f * H + col];
            x0[(size_t)(n0 + rr) * H + col] = f2bf(acc);
        }
    } else if (bid < 2304) {                // ---- WT[c][k] = stacked W^T -> bf16
        int base = bid - 2048;
        const float* __restrict__ Wrel = (base < 128) ? W1_rel : W2_rel;
        const float* __restrict__ Wroot = (base < 128) ? W1_root : W2_root;
        u16* WT = (base < 128) ? WT1 : WT2;
        int i = (base & 127) * 256 + t;
        int c = i >> 8, k = i & 255;
        float v = (k < H) ? Wrel[k * H + c] : Wroot[(k - H) * H + c];
        WT[c * 256 + k] = f2bf(v);
    } else {                                // ---- per-chunk graph histogram
        __shared__ int h[NB];
        if (t < NB) h[t] = 0;
        __syncthreads();
        int ebase = (bid - 2304) * EPB;
        #pragma unroll
        for (int i = 0; i < EPB / 256; ++i) {
            int s = src[ebase + i * 256 + t];
            atomicAdd(&h[s >> 9], 1);
        }
        __syncthreads();
        if (t < NB) histG[(bid - 2304) * NB + t] = h[t];
    }
}

// scan histG -> per-(block,graph) global bases + per-graph bases. 1 block, 1024 threads.
__global__ __launch_bounds__(1024) void k_scanG(const int* __restrict__ histG,
                                                int* __restrict__ startG,
                                                int* __restrict__ gbase) {
    __shared__ int csum[16][64];
    __shared__ int gpre[64];
    int t = threadIdx.x;
    int g = t & 63, c = t >> 6;
    int vals[16];
    int s = 0;
    #pragma unroll
    for (int i = 0; i < 16; ++i) {
        vals[i] = histG[(c * 16 + i) * NB + g];
        s += vals[i];
    }
    csum[c][g] = s;
    __syncthreads();
    int pre = 0;
    for (int i = 0; i < c; ++i) pre += csum[i][g];
    if (c == 0) {
        int tot = 0;
        #pragma unroll
        for (int i = 0; i < 16; ++i) tot += csum[i][g];
        int x = tot;
        #pragma unroll
        for (int o = 1; o < 64; o <<= 1) {
            int y = __shfl_up(x, o);
            if (g >= o) x += y;
        }
        gpre[g] = x - tot;
        gbase[g] = x - tot;
        if (g == 63) gbase[64] = x;
    }
    __syncthreads();
    int run = gpre[g] + pre;
    #pragma unroll
    for (int i = 0; i < 16; ++i) {
        startG[(c * 16 + i) * NB + g] = run;
        run += vals[i];
    }
}

// LDS-staged graph-sort of each 4096-edge chunk -> coalesced writes.
__global__ __launch_bounds__(256) void k_scatterA(
        const int* __restrict__ src, const int* __restrict__ dst,
        const float* __restrict__ ew, const int* __restrict__ histG,
        const int* __restrict__ startG, int2* __restrict__ tmp) {
    __shared__ int lstart[NB + 1];
    __shared__ int cursor[NB];
    __shared__ int gdst[NB];
    __shared__ int2 buf[EPB];   // 32 KB
    int t = threadIdx.x, bid = blockIdx.x;
    if (t < NB) {
        int c = histG[bid * NB + t];
        int x = c;
        #pragma unroll
        for (int o = 1; o < 64; o <<= 1) {
            int y = __shfl_up(x, o);
            if (t >= o) x += y;
        }
        lstart[t] = x - c;
        cursor[t] = x - c;
        gdst[t] = startG[bid * NB + t];
        if (t == 63) lstart[NB] = x;
    }
    __syncthreads();
    int ebase = bid * EPB;
    #pragma unroll
    for (int i = 0; i < EPB / 256; ++i) {
        int e = ebase + i * 256 + t;
        int s = src[e], d = dst[e];
        float w = ew[e];
        int g = s >> 9;
        int meta = (s & 511) | ((d & 511) << 9);
        int p = atomicAdd(&cursor[g], 1);
        buf[p] = make_int2(meta, __float_as_int(w));
    }
    __syncthreads();
    for (int i = t; i < EPB; i += 256) {
        int lo = 0;
        #pragma unroll
        for (int stp = 32; stp; stp >>= 1)
            if (lstart[lo + stp] <= i) lo += stp;
        tmp[gdst[lo] + (i - lstart[lo])] = buf[i];
    }
}

// per-graph counting sort by dst (2 blocks/graph). Emits final CSR + offs.
__global__ __launch_bounds__(512) void k_sortB(
        const int2* __restrict__ tmp, const int* __restrict__ gbase,
        int2* __restrict__ sorted, int* __restrict__ offs) {
    __shared__ int hist[NP];
    __shared__ int start[NP + 1];
    __shared__ int cursor[NP / 2];
    __shared__ int wsum[8];
    __shared__ int perm[CAPH];   // 34 KB
    int t = threadIdx.x;
    int lane = t & 63, wv = t >> 6;
    int g = blockIdx.x >> 1, half = blockIdx.x & 1;
    int gbeg = gbase[g], gend = gbase[g + 1];
    int cnt = gend - gbeg;
    hist[t] = 0;
    __syncthreads();
    for (int i = t; i < cnt; i += 512) {
        int meta = tmp[gbeg + i].x;
        atomicAdd(&hist[(meta >> 9) & 511], 1);
    }
    __syncthreads();
    int c = hist[t];
    int x = c;
    #pragma unroll
    for (int o = 1; o < 64; o <<= 1) {
        int y = __shfl_up(x, o);
        if (lane >= o) x += y;
    }
    if (lane == 63) wsum[wv] = x;
    __syncthreads();
    int off = 0;
    #pragma unroll
    for (int i = 0; i < 8; ++i) off += (i < wv) ? wsum[i] : 0;
    start[t] = off + x - c;
    if (t == 511) start[NP] = off + x;
    __syncthreads();
    int h0 = half * 256;
    if (t < 256) {
        int n = h0 + t;
        offs[g * NP + n] = gbeg + start[n];
        cursor[t] = start[n];
    }
    if (blockIdx.x == 0 && t == 0) offs[NN] = NE;
    __syncthreads();
    int ha = start[h0];
    int hb = half ? cnt : start[256];
    for (int i = t; i < cnt; i += 512) {
        int meta = tmp[gbeg + i].x;
        int d = (meta >> 9) & 511;
        if ((d >> 8) == half) {
            int p = atomicAdd(&cursor[d - h0], 1);
            perm[p - ha] = i;
        }
    }
    __syncthreads();
    for (int o = ha + t; o < hb; o += 512) {
        sorted[gbeg + o] = tmp[gbeg + perm[o - ha]];
    }
}

// fused agg + GEMM: sAgg (LDS) = CSR-agg of 64 rows; Y = [sAgg|X] @ WT^T + brel.
// APPLY_BN: fold previous layer's BN+ReLU into the gather and X-fragments.
template<int APPLY_BN>
__global__ __launch_bounds__(256, 3) void k_ag(
        const u16* __restrict__ X, const int* __restrict__ offs,
        const int2* __restrict__ rec, const u16* __restrict__ WT,
        const float* __restrict__ brel,
        const float* __restrict__ bn_prev, const float* __restrict__ gprev,
        const float* __restrict__ beprev,
        u16* __restrict__ Y, float* __restrict__ bn_out) {
    __shared__ u16 sAgg[64][136];          // +8 pad: conflict-free frag reads
    __shared__ u16 sWT[64][264];           // col-half staging
    __shared__ float colS[128], colQ[128];
    __shared__ float scL[128], shL[128];
    int t = threadIdx.x, b = blockIdx.x;
    int chunk = (b & 7) * 64 + (b >> 3);   // XCD swizzle over 512 chunks
    int row0 = chunk * 64;
    int sbase = row0 & ~(NP - 1);

    if (APPLY_BN) {
        if (t < 128) {
            float su = 0.f, sq = 0.f;
            #pragma unroll
            for (int sh = 0; sh < NSH; ++sh) {
                su += bn_prev[(sh * 2 + 0) * H + t];
                sq += bn_prev[(sh * 2 + 1) * H + t];
            }
            float mu = su * (1.f / NN);
            float var = sq * (1.f / NN) - mu * mu;
            float sc = rsqrtf(var + BN_EPS) * gprev[t];
            scL[t] = sc;
            shL[t] = beprev[t] - mu * sc;
        }
        __syncthreads();
    }

    // ---- phase A: aggregate 64 rows into sAgg ----
    {
        int wv = t >> 6, lane = t & 63;
        const u16* xg = X + (size_t)sbase * H;
        float sc0 = 0.f, sc1 = 0.f, sh0 = 0.f, sh1 = 0.f;
        if (APPLY_BN) {
            sc0 = scL[2 * lane]; sc1 = scL[2 * lane + 1];
            sh0 = shL[2 * lane]; sh1 = shL[2 * lane + 1];
        }
        for (int r = wv; r < 64; r += 4) {
            int node = row0 + r;
            int beg = offs[node], end = offs[node + 1];
            float a0 = 0.f, a1 = 0.f, c0 = 0.f, c1 = 0.f;
            int j = beg;
            for (; j + 4 <= end; j += 4) {
                int2 r0 = rec[j], r1 = rec[j + 1], r2 = rec[j + 2], r3 = rec[j + 3];
                u32 p0 = *(const u32*)(xg + (size_t)(r0.x & 511) * H + 2 * lane);
                u32 p1 = *(const u32*)(xg + (size_t)(r1.x & 511) * H + 2 * lane);
                u32 p2 = *(const u32*)(xg + (size_t)(r2.x & 511) * H + 2 * lane);
                u32 p3 = *(const u32*)(xg + (size_t)(r3.x & 511) * H + 2 * lane);
                float w0 = __int_as_float(r0.y), w1 = __int_as_float(r1.y);
                float w2 = __int_as_float(r2.y), w3 = __int_as_float(r3.y);
                float v00 = bfLo(p0), v01 = bfHi(p0), v10 = bfLo(p1), v11 = bfHi(p1);
                float v20 = bfLo(p2), v21 = bfHi(p2), v30 = bfLo(p3), v31 = bfHi(p3);
                if (APPLY_BN) {
                    v00 = fmaxf(fmaf(v00, sc0, sh0), 0.f); v01 = fmaxf(fmaf(v01, sc1, sh1), 0.f);
                    v10 = fmaxf(fmaf(v10, sc0, sh0), 0.f); v11 = fmaxf(fmaf(v11, sc1, sh1), 0.f);
                    v20 = fmaxf(fmaf(v20, sc0, sh0), 0.f); v21 = fmaxf(fmaf(v21, sc1, sh1), 0.f);
                    v30 = fmaxf(fmaf(v30, sc0, sh0), 0.f); v31 = fmaxf(fmaf(v31, sc1, sh1), 0.f);
                }
                a0 += w0 * v00; a1 += w0 * v01;
                c0 += w1 * v10; c1 += w1 * v11;
                a0 += w2 * v20; a1 += w2 * v21;
                c0 += w3 * v30; c1 += w3 * v31;
            }
            for (; j < end; ++j) {
                int2 r = rec[j];
                u32 p = *(const u32*)(xg + (size_t)(r.x & 511) * H + 2 * lane);
                float w = __int_as_float(r.y);
                float v0 = bfLo(p), v1 = bfHi(p);
                if (APPLY_BN) {
                    v0 = fmaxf(fmaf(v0, sc0, sh0), 0.f);
                    v1 = fmaxf(fmaf(v1, sc1, sh1), 0.f);
                }
                a0 += w * v0; a1 += w * v1;
            }
            a0 += c0; a1 += c1;
            *(u32*)&sAgg[r][2 * lane] = (u32)f2bf(a0) | ((u32)f2bf(a1) << 16);
        }
    }
    if (t < 128) { colS[t] = 0.f; colQ[t] = 0.f; }
    __syncthreads();

    // ---- phase B: MFMA gemm, 2 col-half passes ----
    int w = t >> 6, lane = t & 63;
    int lr = lane & 15, lg = lane >> 4;
    int myrl = w * 16 + lr;
    bf16x8 af[8];
    #pragma unroll
    for (int kt = 0; kt < 4; ++kt)
        af[kt] = *(const bf16x8*)&sAgg[myrl][kt * 32 + lg * 8];
    const u16* px = X + (size_t)(row0 + myrl) * H + lg * 8;
    #pragma unroll
    for (int kt = 0; kt < 4; ++kt) {
        bf16x8 rx = *(const bf16x8*)(px + kt * 32);
        if (APPLY_BN) {
            bf16x8 o;
            #pragma unroll
            for (int j = 0; j < 8; ++j) {
                int cc = kt * 32 + lg * 8 + j;
                float v = fmaxf(fmaf(b2f((u16)rx[j]), scL[cc], shL[cc]), 0.f);
                o[j] = (short)f2bf(v);
            }
            af[4 + kt] = o;
        } else {
            af[4 + kt] = rx;
        }
    }

    #pragma unroll
    for (int colh = 0; colh < 2; ++colh) {
        int col0 = colh * 64;
        __syncthreads();
        for (int i = t; i < 64 * 32; i += 256) {
            int r = i >> 5, c = i & 31;
            *(uint4*)&sWT[r][c * 8] = *(const uint4*)(WT + (size_t)(col0 + r) * 256 + c * 8);
        }
        __syncthreads();
        f32x4 acc[4];
        #pragma unroll
        for (int nt = 0; nt < 4; ++nt) acc[nt] = (f32x4){0.f, 0.f, 0.f, 0.f};
        #pragma unroll
        for (int kt = 0; kt < 8; ++kt) {
            #pragma unroll
            for (int nt = 0; nt < 4; ++nt) {
                bf16x8 bf = *(const bf16x8*)&sWT[nt * 16 + lr][kt * 32 + lg * 8];
                acc[nt] = __builtin_amdgcn_mfma_f32_16x16x32_bf16(af[kt], bf, acc[nt], 0, 0, 0);
            }
        }
        #pragma unroll
        for (int nt = 0; nt < 4; ++nt) {
            int col = col0 + nt * 16 + lr;
            float bias = brel[col];
            float s = 0.f, q = 0.f;
            #pragma unroll
            for (int j = 0; j < 4; ++j) {
                float v = acc[nt][j] + bias;
                int row = row0 + w * 16 + lg * 4 + j;
                Y[(size_t)row * H + col] = f2bf(v);
                s += v; q += v * v;
            }
            s += __shfl_xor(s, 16); s += __shfl_xor(s, 32);
            q += __shfl_xor(q, 16); q += __shfl_xor(q, 32);
            if (lg == 0) {
                atomicAdd(&colS[col], s);
                atomicAdd(&colQ[col], q);
            }
        }
    }
    __syncthreads();
    if (t < 128) {
        int sh = b & (NSH - 1);
        atomicAdd(&bn_out[(sh * 2 + 0) * H + t], colS[t]);
        atomicAdd(&bn_out[(sh * 2 + 1) * H + t], colQ[t]);
    }
}

// BN2 finalize + ReLU + s = softmax(x@W_pool+b_pool) + pool partials (no x write-back).
__global__ __launch_bounds__(256) void k_bnrelu_s(const u16* __restrict__ y,
        const float* __restrict__ bn_base, const float* __restrict__ g,
        const float* __restrict__ be, const float* __restrict__ Wp,
        const float* __restrict__ bp, float* __restrict__ s,
        float* __restrict__ pool) {
    __shared__ float scL[H], shL[H];
    __shared__ float poolL[256];
    int t = threadIdx.x;
    if (t < H) {
        float su = 0.f, sq = 0.f;
        #pragma unroll
        for (int sh = 0; sh < NSH; ++sh) {
            su += bn_base[(sh * 2 + 0) * H + t];
            sq += bn_base[(sh * 2 + 1) * H + t];
        }
        float mu = su * (1.f / NN);
        float var = sq * (1.f / NN) - mu * mu;
        float sc = rsqrtf(var + BN_EPS) * g[t];
        scL[t] = sc;
        shL[t] = be[t] - mu * sc;
    }
    poolL[t] = 0.f;
    __syncthreads();
    int graph = blockIdx.x >> 3;
    int c = (t & 15) * 8;
    float pa0[8], pa1[8];
    #pragma unroll
    for (int j = 0; j < 8; ++j) { pa0[j] = 0.f; pa1[j] = 0.f; }
    #pragma unroll
    for (int it = 0; it < 4; ++it) {
        int idx = blockIdx.x * 1024 + it * 256 + t;
        uint4 u = ((const uint4*)y)[idx];
        u32 uu[4] = {u.x, u.y, u.z, u.w};
        float v[8];
        #pragma unroll
        for (int p = 0; p < 4; ++p) {
            v[2 * p] = fmaxf(fmaf(bfLo(uu[p]), scL[c + 2 * p], shL[c + 2 * p]), 0.f);
            v[2 * p + 1] = fmaxf(fmaf(bfHi(uu[p]), scL[c + 2 * p + 1], shL[c + 2 * p + 1]), 0.f);
        }
        float z0 = 0.f, z1 = 0.f;
        #pragma unroll
        for (int j = 0; j < 8; ++j) {
            z0 += v[j] * Wp[(c + j) * 2];
            z1 += v[j] * Wp[(c + j) * 2 + 1];
        }
        #pragma unroll
        for (int o2 = 8; o2; o2 >>= 1) { z0 += __shfl_xor(z0, o2); z1 += __shfl_xor(z1, o2); }
        z0 += bp[0]; z1 += bp[1];
        float m = fmaxf(z0, z1);
        float e0 = expf(z0 - m), e1 = expf(z1 - m);
        float inv = 1.f / (e0 + e1);
        float s0 = e0 * inv, s1 = e1 * inv;
        int row = idx >> 4;
        if ((t & 15) == 0) { s[row * 2] = s0; s[row * 2 + 1] = s1; }
        #pragma unroll
        for (int j = 0; j < 8; ++j) { pa0[j] += s0 * v[j]; pa1[j] += s1 * v[j]; }
    }
    #pragma unroll
    for (int j = 0; j < 8; ++j) {
        atomicAdd(&poolL[c + j], pa0[j]);
        atomicAdd(&poolL[128 + c + j], pa1[j]);
    }
    __syncthreads();
    if (t < 128) atomicAdd(&pool[(graph * 2 + 0) * H + t], poolL[t]);
    else atomicAdd(&pool[(graph * 2 + 1) * H + (t - 128)], poolL[t]);
}

// b<256: edge stats (+graph stats on q==0; last block computes losses)
// b in [256,320): logits for graph b-256.
__global__ __launch_bounds__(256) void k_edge_logits(
        const int2* __restrict__ sorted, const int* __restrict__ gbase,
        const float* __restrict__ s, const float* __restrict__ pool,
        const float* __restrict__ Wpost, const float* __restrict__ bpost,
        float* __restrict__ num, float* __restrict__ den,
        float* __restrict__ gst, int* __restrict__ ctr,
        float* __restrict__ out) {
    int t = threadIdx.x, b = blockIdx.x;
    if (b >= 256) {   // ---- logits
        int gb = b - 256;
        float v = pool[gb * 256 + t];
        v = v > 0.f ? v : 0.f;
        float p0 = v * Wpost[t * 2], p1 = v * Wpost[t * 2 + 1];
        for (int o = 32; o; o >>= 1) { p0 += __shfl_down(p0, o); p1 += __shfl_down(p1, o); }
        __shared__ float t0[4], t1[4];
        if ((t & 63) == 0) { t0[t >> 6] = p0; t1[t >> 6] = p1; }
        __syncthreads();
        if (t == 0) {
            out[gb * 2] = t0[0] + t0[1] + t0[2] + t0[3] + bpost[0];
            out[gb * 2 + 1] = t1[0] + t1[1] + t1[2] + t1[3] + bpost[1];
        }
        return;
    }
    // ---- edge stats
    __shared__ float2 sl[NP];
    __shared__ float ln[4], ld2[4];
    __shared__ int lastFlag;
    int g = b >> 2, q = b & 3;
    int gbeg = gbase[g], gend = gbase[g + 1];
    for (int i = t; i < NP; i += 256) sl[i] = ((const float2*)s)[g * NP + i];
    __syncthreads();
    float an = 0.f, ad = 0.f;
    int cnt = gend - gbeg;
    int q0 = gbeg + (cnt * q) / 4, q1 = gbeg + (cnt * (q + 1)) / 4;
    for (int i = q0 + t; i < q1; i += 256) {
        int2 r = sorted[i];
        float w = __int_as_float(r.y);
        float2 ss = sl[r.x & 511];
        float2 sd = sl[(r.x >> 9) & 511];
        an += w * (ss.x * sd.x + ss.y * sd.y);
        ad += w * (ss.x * ss.x + ss.y * ss.y);
    }
    for (int o = 32; o; o >>= 1) { an += __shfl_down(an, o); ad += __shfl_down(ad, o); }
    if ((t & 63) == 0) { ln[t >> 6] = an; ld2[t >> 6] = ad; }
    __syncthreads();
    if (t == 0) {
        atomicAdd(&num[g], ln[0] + ln[1] + ln[2] + ln[3]);
        atomicAdd(&den[g], ld2[0] + ld2[1] + ld2[2] + ld2[3]);
    }
    if (q == 0) {
        float p00 = 0.f, p01 = 0.f, p11 = 0.f;
        for (int i = t; i < NP; i += 256) {
            float2 sv = sl[i];
            p00 += sv.x * sv.x;
            p01 += sv.x * sv.y;
            p11 += sv.y * sv.y;
        }
        for (int o = 32; o; o >>= 1) {
            p00 += __shfl_down(p00, o);
            p01 += __shfl_down(p01, o);
            p11 += __shfl_down(p11, o);
        }
        __shared__ float tp[3][4];
        if ((t & 63) == 0) {
            int w = t >> 6;
            tp[0][w] = p00; tp[1][w] = p01; tp[2][w] = p11;
        }
        __syncthreads();
        if (t == 0) {
            atomicAdd(&gst[g], tp[0][0] + tp[0][1] + tp[0][2] + tp[0][3]);
            atomicAdd(&gst[NB + g], tp[1][0] + tp[1][1] + tp[1][2] + tp[1][3]);
            atomicAdd(&gst[2 * NB + g], tp[2][0] + tp[2][1] + tp[2][2] + tp[2][3]);
        }
    }
    // ---- last-block-done: losses
    if (t == 0) {
        __threadfence();
        int old = atomicAdd(ctr, 1);
        lastFlag = (old == 255);
    }
    __syncthreads();
    if (lastFlag && t < 64) {
        float nv = atomicAdd(&num[t], 0.f);
        float dv = atomicAdd(&den[t], 0.f);
        float s00 = atomicAdd(&gst[t], 0.f);
        float s01 = atomicAdd(&gst[NB + t], 0.f);
        float s11 = atomicAdd(&gst[2 * NB + t], 0.f);
        float mc = -(nv / dv);
        float nrm = sqrtf(s00 * s00 + 2.f * s01 * s01 + s11 * s11);
        const float a = 0.70710678118654752440f;
        float d00 = s00 / nrm - a, d01 = s01 / nrm, d11 = s11 / nrm - a;
        float ol = sqrtf(d00 * d00 + 2.f * d01 * d01 + d11 * d11);
        for (int o = 32; o; o >>= 1) { mc += __shfl_down(mc, o); ol += __shfl_down(ol, o); }
        if (t == 0) {
            out[NB * 2] = mc * (1.f / NB);
            out[NB * 2 + 1] = ol * (1.f / NB);
        }
    }
}

// ---------------- launch ----------------
extern "C" void kernel_launch(void* const* d_in, const int* in_sizes, int n_in,
                              void* d_out, int out_size, void* d_ws, size_t ws_size,
                              hipStream_t stream) {
    const float* nf     = (const float*)d_in[0];
    const int*   ei     = (const int*)d_in[1];
    const float* ew     = (const float*)d_in[2];
    const float* W_pre  = (const float*)d_in[4];
    const float* b_pre  = (const float*)d_in[5];
    const float* W1_rel = (const float*)d_in[6];
    const float* b1_rel = (const float*)d_in[7];
    const float* W1_root= (const float*)d_in[8];
    const float* g1     = (const float*)d_in[9];
    const float* be1    = (const float*)d_in[10];
    const float* W2_rel = (const float*)d_in[11];
    const float* b2_rel = (const float*)d_in[12];
    const float* W2_root= (const float*)d_in[13];
    const float* g2     = (const float*)d_in[14];
    const float* be2    = (const float*)d_in[15];
    const float* W_pool = (const float*)d_in[16];
    const float* b_pool = (const float*)d_in[17];
    const float* W_post = (const float*)d_in[18];
    const float* b_post = (const float*)d_in[19];

    char* ws = (char*)d_ws;
    u16*   bufX   = (u16*)(ws + OFF_X);
    u16*   bufY   = (u16*)(ws + OFF_Y);
    int2*  tmp    = (int2*)(ws + OFF_TMP);
    int2*  sorted = (int2*)(ws + OFF_SORT);
    int*   offs   = (int*)(ws + OFF_OFFS);
    int*   histG  = (int*)(ws + OFF_HISTG);
    int*   startG = (int*)(ws + OFF_STARTG);
    int*   gbase  = (int*)(ws + OFF_GBASE);
    u16*   WT1    = (u16*)(ws + OFF_WT1);
    u16*   WT2    = (u16*)(ws + OFF_WT2);
    float* sarr   = (float*)(ws + OFF_S);
    float* gst    = (float*)(ws + OFF_GST);
    float* numA   = (float*)(ws + OFF_NUM);
    float* denA   = (float*)(ws + OFF_DEN);
    int*   ctr    = (int*)(ws + OFF_CTR);
    float* bn     = (float*)(ws + OFF_BN);
    float* pool   = (float*)(ws + OFF_POOL);
    float* outF   = (float*)d_out;

    const int* srcA = ei;
    const int* dstA = ei + NE;
    float* bn1 = bn;
    float* bn2 = (float*)(ws + OFF_BN + SZ_BNL);

    hipMemsetAsync(ws + OFF_ZERO, 0, ZERO_BYTES, stream);

    k_prep<<<2560, 256, 0, stream>>>(nf, W_pre, b_pre, W1_rel, W1_root,
                                     W2_rel, W2_root, srcA, bufX, WT1, WT2, histG);
    k_scanG<<<1, 1024, 0, stream>>>(histG, startG, gbase);
    k_scatterA<<<NBLK, 256, 0, stream>>>(srcA, dstA, ew, histG, startG, tmp);
    k_sortB<<<2 * NB, 512, 0, stream>>>(tmp, gbase, sorted, offs);

    // layer 1: agg+gemm fused (x0 -> y1)
    k_ag<0><<<NN / 64, 256, 0, stream>>>(bufX, offs, sorted, WT1, b1_rel,
                                         nullptr, nullptr, nullptr, bufY, bn1);
    // layer 2: BN1+ReLU folded into agg+gemm (y1 -> y2)
    k_ag<1><<<NN / 64, 256, 0, stream>>>(bufY, offs, sorted, WT2, b2_rel,
                                         bn1, g1, be1, bufX, bn2);
    // BN2+ReLU + softmax s + pool
    k_bnrelu_s<<<512, 256, 0, stream>>>(bufX, bn2, g2, be2, W_pool, b_pool, sarr, pool);
    // edge stats + logits + losses
    k_edge_logits<<<320, 256, 0, stream>>>(sorted, gbase, sarr, pool, W_post, b_post,
                                           numA, denA, gst, ctr, outF);
}